// Round 3
// baseline (21.268 us; speedup 1.0000x reference)
//
#include <hip/hip_runtime.h>

#define HH 128
#define WW 128
#define CC 3
#define TX 8
#define TY 8
#define NPIX 64
#define IW 18                 // image tile dim (8 + 2*5 halo)
#define NIMG (IW*IW)          // 324
#define SW 12                 // stats dim (8 + 2*2 halo)
#define NST (SW*SW)           // 144
#define PSTRIDE 25            // odd stride -> 2-way LDS aliasing (free)
#define NTHR 384              // 64 px * 3 ch * 2 neighbor-halves

__global__ __launch_bounds__(NTHR, 3)
void err_neurons_kernel(const float* __restrict__ img, float* __restrict__ out) {
    __shared__ float s_img[CC][NIMG];
    __shared__ float s_rs[CC][IW][SW];    // 7-wide row sums
    __shared__ float s_rs2[CC][IW][SW];   // 7-wide row sums of squares
    __shared__ float s_mu[CC][NST];
    __shared__ float s_r[CC][NST];
    __shared__ float s_nsq[CC][NST];
    __shared__ float s_rnrm[NST];
    __shared__ float s_part[CC][NPIX * PSTRIDE];

    const int tid = threadIdx.x;
    const int x0 = blockIdx.x * TX, y0 = blockIdx.y * TY;
    const float* imgb = img + (size_t)blockIdx.z * CC * HH * WW;

    // ---- Phase 1: stage zero-padded 18x18 tiles, 3 channels ----
    for (int i = tid; i < CC * NIMG; i += NTHR) {
        const int c = i / NIMG, r = i % NIMG;
        const int iy = r / IW, ix = r % IW;
        const int yy = y0 - 5 + iy, xx = x0 - 5 + ix;
        float v = 0.f;
        if ((unsigned)yy < HH && (unsigned)xx < WW)
            v = imgb[(size_t)c * HH * WW + yy * WW + xx];
        s_img[c][r] = v;
    }
    __syncthreads();

    // ---- Phase 2a: separable stats, horizontal 7-wide sums ----
    for (int u2 = tid; u2 < CC * IW * SW; u2 += NTHR) {
        const int c = u2 / (IW * SW);
        const int rem = u2 % (IW * SW);
        const int r = rem / SW, sx = rem % SW;
        const float* bp = &s_img[c][r * IW + sx];
        float s = 0.f, s2 = 0.f;
#pragma unroll
        for (int j = 0; j < 7; ++j) { float v = bp[j]; s += v; s2 = fmaf(v, v, s2); }
        s_rs[c][r][sx] = s; s_rs2[c][r][sx] = s2;
    }
    __syncthreads();

    // ---- Phase 2b: vertical 7-tall sums -> mu, rsqrt(var+eps), norm^2 ----
    for (int u2 = tid; u2 < CC * NST; u2 += NTHR) {
        const int c = u2 / NST;
        const int pos = u2 % NST;
        const int sy = pos / SW, sx = pos % SW;
        float s = 0.f, s2 = 0.f;
#pragma unroll
        for (int i = 0; i < 7; ++i) { s += s_rs[c][sy + i][sx]; s2 += s_rs2[c][sy + i][sx]; }
        const float mu  = s * (1.f / 49.f);
        const float var = fmaxf(fmaf(-mu, mu, s2 * (1.f / 49.f)), 0.f);
        const float rr  = rsqrtf(var + 1e-5f);
        s_mu[c][pos] = mu;
        s_r[c][pos]  = rr;
        s_nsq[c][pos] = fmaf(49.f * var, rr * rr, 196.f);  // ||f_c||^2
    }
    __syncthreads();
    if (tid < NST)
        s_rnrm[tid] = rsqrtf(s_nsq[0][tid] + s_nsq[1][tid] + s_nsq[2][tid]);
    __syncthreads();

    // ---- Phase 3: cross-correlations; thread = (pixel, channel, nb-half) ----
    {
        const int p = tid & 63;
        const int g = tid >> 6;          // wave-uniform
        const int c = g % 3, h = g / 3;  // h = neighbor half
        const int x = p & 7, y = p >> 3;
        const int row0 = y + 2 * h;      // window base row in s_img
        float W[9][11];
#pragma unroll
        for (int r = 0; r < 9; ++r)
#pragma unroll
            for (int q = 0; q < 11; ++q)
                W[r][q] = s_img[c][(row0 + r) * IW + x + q];
        const int spos = (y + 2) * SW + (x + 2);
        const float mut = s_mu[c][spos];
        const float rt  = s_r[c][spos];
        float* partp = &s_part[c][p * PSTRIDE];
        if (h == 0) {
            // neighbors u = 0..11 (dy in {-2,-1,0-}), window rows y-5..y+3, c0 = 2
#pragma unroll
            for (int j = 0; j < 12; ++j) {
                const int dy = j / 5 - 2, dx = j % 5 - 2;
                float cross = 0.f;
#pragma unroll
                for (int oy = 0; oy < 7; ++oy)
#pragma unroll
                    for (int ox = 0; ox < 7; ++ox)
                        cross = fmaf(W[2 + oy][2 + ox], W[2 + dy + oy][2 + dx + ox], cross);
                const int upos = (y + 2 + dy) * SW + (x + 2 + dx);
                partp[j] = fmaf(-49.f * mut, s_mu[c][upos], cross) * (rt * s_r[c][upos]);
            }
        } else {
            // neighbors u = 13..24 (dy in {0+,1,2}), window rows y-3..y+5, c0 = 0
#pragma unroll
            for (int j = 0; j < 12; ++j) {
                const int u = j + 13;
                const int dy = u / 5 - 2, dx = u % 5 - 2;
                float cross = 0.f;
#pragma unroll
                for (int oy = 0; oy < 7; ++oy)
#pragma unroll
                    for (int ox = 0; ox < 7; ++ox)
                        cross = fmaf(W[oy][2 + ox], W[dy + oy][2 + dx + ox], cross);
                const int upos = (y + 2 + dy) * SW + (x + 2 + dx);
                partp[j + 12] = fmaf(-49.f * mut, s_mu[c][upos], cross) * (rt * s_r[c][upos]);
            }
        }
    }
    __syncthreads();

    // ---- Phase 4: combine channels, cosine, masked mean ----
    if (tid < NPIX) {
        const int p = tid, x = p & 7, y = p >> 3;
        const int gx = x0 + x, gy = y0 + y;
        const float rnt = s_rnrm[(y + 2) * SW + (x + 2)];
        float csum = 0.f, cnt = 0.f;
#pragma unroll
        for (int u = 0; u < 25; ++u) {
            if (u == 12) continue;
            const int dy = u / 5 - 2, dx = u % 5 - 2;
            const int j = u - (u > 12 ? 1 : 0);
            if ((unsigned)(gy + dy) >= HH || (unsigned)(gx + dx) >= WW) continue;
            const float dot = 588.f + s_part[0][p * PSTRIDE + j]
                                    + s_part[1][p * PSTRIDE + j]
                                    + s_part[2][p * PSTRIDE + j];
            csum += dot * rnt * s_rnrm[(y + 2 + dy) * SW + (x + 2 + dx)];
            cnt += 1.f;
        }
        out[(size_t)blockIdx.z * HH * WW + gy * WW + gx] = 0.5f - csum / (2.f * cnt);
    }
}

extern "C" void kernel_launch(void* const* d_in, const int* in_sizes, int n_in,
                              void* d_out, int out_size, void* d_ws, size_t ws_size,
                              hipStream_t stream) {
    const float* img = (const float*)d_in[0];
    float* out = (float*)d_out;
    dim3 grid(WW / TX, HH / TY, 2);
    dim3 block(NTHR);
    hipLaunchKernelGGL(err_neurons_kernel, grid, block, 0, stream, img, out);
}